// Round 1
// 873.016 us; speedup vs baseline: 1.0046x; 1.0046x over previous
//
#include <hip/hip_runtime.h>
#include <hip/hip_bf16.h>

#define CI 2048
#define CO_N 2048
#define SLOT 64
#define SPC 4
#define NELEM (CI*SPC*SLOT)          // 524288
#define CAP 256                      // SPC*SLOT per capsule
#define IJ (CI*SPC)                  // 8192
#define S_SPLIT 8                    // ij partitions in k4
#define NC 32                        // 32-ij chunks per k4 block (1024/32)

typedef __attribute__((ext_vector_type(8))) short short8;
typedef __attribute__((ext_vector_type(4))) short short4v;
typedef __attribute__((ext_vector_type(4))) float float4v;

union ABFrag { short4v h[2]; short8 v; };

__device__ __forceinline__ unsigned short f2bf(float f) {
    __hip_bfloat16 h = __float2bfloat16(f);   // RNE
    return __builtin_bit_cast(unsigned short, h);
}

__device__ __forceinline__ float gelu_tanh(float x) {
    const float c0 = 0.7978845608028654f; // sqrt(2/pi)
    float x3 = x * x * x;
    float t = tanhf(c0 * (x + 0.044715f * x3));
    return 0.5f * x * (1.0f + t);
}

// K1: y[i,l,j] = sum_{k,m} Wi[i,j,k,l,m] * x[i,m,k]
// Shuffle-free: thread t owns output (j = t>>2, l = t&3); loops k.
// Per iter: 1 global float4 (Wi[i,j,k,l,0..3]) + 1 broadcast LDS float4 (x[i,:,k]) + 4 FMA.
__global__ __launch_bounds__(256) void k1_capsule_mm(
    const float* __restrict__ x, const float* __restrict__ Wi,
    float* __restrict__ y, float* __restrict__ psum, float* __restrict__ psumsq)
{
    __shared__ float xs[CAP];        // repacked [k][m]: xs[k*4+m] = x[i,m,k]
    __shared__ float ws_s[4], ws_q[4];
    const int i = blockIdx.x;
    const int t = threadIdx.x;
    {
        const int m = t >> 6, k = t & 63;
        xs[k * 4 + m] = x[(size_t)i * CAP + t];
    }
    __syncthreads();

    const int j = t >> 2;            // 0..63 (slot)
    const int l = t & 3;             // 0..3  (spc)
    // Wi strides: i:65536, j:1024, k:16, l:4, m:1 (floats)
    const float* Wb = Wi + (size_t)i * 65536 + j * 1024 + l * 4;
    float p = 0.f;
    #pragma unroll 8
    for (int k = 0; k < 64; ++k) {
        float4 wv = *(const float4*)(Wb + k * 16);
        float4 xv = *(const float4*)(xs + k * 4);
        p += wv.x * xv.x + wv.y * xv.y + wv.z * xv.z + wv.w * xv.w;
    }
    float g = gelu_tanh(p);
    y[(size_t)i * CAP + l * 64 + j] = g;

    // block stats for global LayerNorm
    float s = g, q = g * g;
    #pragma unroll
    for (int off = 32; off > 0; off >>= 1) {
        s += __shfl_down(s, off);
        q += __shfl_down(q, off);
    }
    const int w = t >> 6;
    if ((t & 63) == 0) { ws_s[w] = s; ws_q[w] = q; }
    __syncthreads();
    if (t == 0) {
        psum[i]   = ws_s[0] + ws_s[1] + ws_s[2] + ws_s[3];
        psumsq[i] = ws_q[0] + ws_q[1] + ws_q[2] + ws_q[3];
    }
}

// K3: per-block redundant stats reduce (psum/psumsq are L2-hot, 16 KB) +
// LayerNorm apply + bf16 convert + transpose to ynT[m][ij].
__global__ __launch_bounds__(256) void k3_norm_t(
    const float* __restrict__ y, const float* __restrict__ scale,
    const float* __restrict__ bias, const float* __restrict__ psum,
    const float* __restrict__ psumsq, unsigned short* __restrict__ ynT)
{
    __shared__ float as[4], aq[4];
    __shared__ float sh_mu, sh_inv;
    const int c = blockIdx.x;        // 0..255
    const int t = threadIdx.x;

    float s = 0.f, q = 0.f;
    #pragma unroll
    for (int b = t; b < CI; b += 256) { s += psum[b]; q += psumsq[b]; }
    #pragma unroll
    for (int off = 32; off > 0; off >>= 1) {
        s += __shfl_down(s, off);
        q += __shfl_down(q, off);
    }
    if ((t & 63) == 0) { as[t >> 6] = s; aq[t >> 6] = q; }
    __syncthreads();
    if (t == 0) {
        float S = as[0] + as[1] + as[2] + as[3];
        float Q = aq[0] + aq[1] + aq[2] + aq[3];
        float mu = S / (float)NELEM;
        float var = Q / (float)NELEM - mu * mu;
        sh_mu = mu;
        sh_inv = rsqrtf(var + 1e-6f);
    }
    __syncthreads();
    const float mu = sh_mu, inv = sh_inv;

    const int base = c * 2048 + t * 8;
    float4 ya = *(const float4*)(y + base);
    float4 yb = *(const float4*)(y + base + 4);
    float4 sa = *(const float4*)(scale + base);
    float4 sb = *(const float4*)(scale + base + 4);
    float4 ba = *(const float4*)(bias + base);
    float4 bb = *(const float4*)(bias + base + 4);
    const int ij = c * 32 + (t >> 3);
    const int m0 = (t & 7) * 8;
    float v[8] = { (ya.x-mu)*inv*sa.x+ba.x, (ya.y-mu)*inv*sa.y+ba.y,
                   (ya.z-mu)*inv*sa.z+ba.z, (ya.w-mu)*inv*sa.w+ba.w,
                   (yb.x-mu)*inv*sb.x+bb.x, (yb.y-mu)*inv*sb.y+bb.y,
                   (yb.z-mu)*inv*sb.z+bb.z, (yb.w-mu)*inv*sb.w+bb.w };
    #pragma unroll
    for (int e = 0; e < 8; ++e)
        ynT[(size_t)(m0 + e) * IJ + ij] = f2bf(v[e]);
}

// K4: out[kl,m] = sum_ij Co[ij,kl] * yn[ij,m] via mfma_f32_16x16x32_bf16
// Double-buffered LDS A-tile (one barrier per chunk) + register prefetch of
// both the next Co chunk and the next B fragments (ynT, L2-resident).
__global__ __launch_bounds__(256) void k4_route_mfma(
    const float* __restrict__ Co, const unsigned short* __restrict__ ynT,
    float* __restrict__ out, float* __restrict__ partial, int use_partial)
{
    __shared__ unsigned short lds_a[2][64 * 36];   // 64 kl rows x 32 ij (+4 pad)
    const int t    = threadIdx.x;
    const int kb   = blockIdx.x;        // 0..127
    const int pc   = blockIdx.y;        // 0..7
    const int klb  = kb * 64;
    const int w    = t >> 6;
    const int lane = t & 63;
    const int quad = lane >> 4;
    const int n16  = lane & 15;

    const int p  = t >> 4;              // 0..15: ij pair (2p, 2p+1)
    const int c4 = (t & 15) * 4;        // kl column group

    const float* co_base = Co + ((size_t)(pc * 1024 + 2 * p)) * IJ + klb + c4;
    const unsigned short* ynT_base = ynT + (size_t)(pc * 1024) + quad * 8;

    float4v acc[4];
    #pragma unroll
    for (int mt = 0; mt < 4; ++mt) acc[mt] = (float4v)(0.f);

    // prologue: chunk 0 operands
    float4 co0 = *(const float4*)(co_base);
    float4 co1 = *(const float4*)(co_base + IJ);
    short8 bcur[4], bnxt[4];
    #pragma unroll
    for (int mt = 0; mt < 4; ++mt)
        bcur[mt] = *(const short8*)(ynT_base + (size_t)(mt * 16 + n16) * IJ);

    for (int g = 0; g < NC; ++g) {
        unsigned int* lw = (unsigned int*)lds_a[g & 1];
        lw[(c4 + 0) * 18 + p] = (unsigned int)f2bf(co0.x) | ((unsigned int)f2bf(co1.x) << 16);
        lw[(c4 + 1) * 18 + p] = (unsigned int)f2bf(co0.y) | ((unsigned int)f2bf(co1.y) << 16);
        lw[(c4 + 2) * 18 + p] = (unsigned int)f2bf(co0.z) | ((unsigned int)f2bf(co1.z) << 16);
        lw[(c4 + 3) * 18 + p] = (unsigned int)f2bf(co0.w) | ((unsigned int)f2bf(co1.w) << 16);
        __syncthreads();    // writes of buf[g&1] visible; prior buffer's readers done

        if (g + 1 < NC) {   // prefetch next chunk (Co from HBM, B from L2)
            const float* nb = co_base + (size_t)(g + 1) * 32 * IJ;
            co0 = *(const float4*)(nb);
            co1 = *(const float4*)(nb + IJ);
            const unsigned short* yb = ynT_base + (size_t)(g + 1) * 32;
            #pragma unroll
            for (int mt = 0; mt < 4; ++mt)
                bnxt[mt] = *(const short8*)(yb + (size_t)(mt * 16 + n16) * IJ);
        }

        // A fragment: kl = klb + w*16 + n16, ij = chunk + quad*8 .. +8
        const unsigned short* arow = lds_a[g & 1] + (w * 16 + n16) * 36 + quad * 8;
        ABFrag af;
        af.h[0] = *(const short4v*)(arow);
        af.h[1] = *(const short4v*)(arow + 4);
        #pragma unroll
        for (int mt = 0; mt < 4; ++mt)
            acc[mt] = __builtin_amdgcn_mfma_f32_16x16x32_bf16(af.v, bcur[mt], acc[mt], 0, 0, 0);

        if (g + 1 < NC) {
            #pragma unroll
            for (int mt = 0; mt < 4; ++mt) bcur[mt] = bnxt[mt];
        }
    }

    // D layout: row(kl) = quad*4 + reg, col(m) = n16
    if (use_partial) {
        float* pp = partial + (size_t)pc * NELEM;
        #pragma unroll
        for (int mt = 0; mt < 4; ++mt)
            #pragma unroll
            for (int r = 0; r < 4; ++r)
                pp[(size_t)(klb + w * 16 + quad * 4 + r) * 64 + mt * 16 + n16] = acc[mt][r];
    } else {
        #pragma unroll
        for (int mt = 0; mt < 4; ++mt)
            #pragma unroll
            for (int r = 0; r < 4; ++r)
                atomicAdd(out + (size_t)(klb + w * 16 + quad * 4 + r) * 64 + mt * 16 + n16, acc[mt][r]);
    }
}

// K5: reduce 8 partials -> out (partial path only)
__global__ __launch_bounds__(256) void k5_reduce(
    const float* __restrict__ partial, float* __restrict__ out)
{
    const int idx = blockIdx.x * 256 + threadIdx.x;
    float s = 0.f;
    #pragma unroll
    for (int pcs = 0; pcs < S_SPLIT; ++pcs) s += partial[(size_t)pcs * NELEM + idx];
    out[idx] = s;
}

extern "C" void kernel_launch(void* const* d_in, const int* in_sizes, int n_in,
                              void* d_out, int out_size, void* d_ws, size_t ws_size,
                              hipStream_t stream) {
    const float* x        = (const float*)d_in[0];
    const float* Wi       = (const float*)d_in[1];
    const float* ln_scale = (const float*)d_in[2];
    const float* ln_bias  = (const float*)d_in[3];
    const float* Co       = (const float*)d_in[4];
    float* out = (float*)d_out;

    float* ws = (float*)d_ws;
    float* y      = ws;                       // 524288 floats
    float* psum   = y + NELEM;                // 2048
    float* psumsq = psum + CI;                // 2048
    unsigned short* ynT = (unsigned short*)(ws + 528392);   // 524288 ushorts (16B-aligned)
    float* partial = ws + 790536;             // 8 * 524288 floats (partial path)

    const int use_partial = (ws_size >= (size_t)(790536 + S_SPLIT * NELEM) * sizeof(float)) ? 1 : 0;

    k1_capsule_mm<<<CI, 256, 0, stream>>>(x, Wi, y, psum, psumsq);
    k3_norm_t<<<256, 256, 0, stream>>>(y, ln_scale, ln_bias, psum, psumsq, ynT);
    if (!use_partial)
        hipMemsetAsync(out, 0, (size_t)out_size * sizeof(float), stream);
    k4_route_mfma<<<dim3(128, S_SPLIT), 256, 0, stream>>>(Co, ynT, out, partial, use_partial);
    if (use_partial)
        k5_reduce<<<NELEM / 256, 256, 0, stream>>>(partial, out);
}